// Round 11
// baseline (37.950 us; speedup 1.0000x reference)
//
#include <hip/hip_runtime.h>
#include <hip/hip_bf16.h>
#include <math.h>

#define S_SAMPLED 1000
#define SPAD      1024
#define DIM       512
#define BATCH     8192

#define BM 64
#define BN 256
#define BKT 32                 // K per tile: A f32 128 B/row, B bf16 64 B/row
#define KTILES (DIM / BKT)     // 16
#define NCHUNK 4               // SPAD / BN
#define GEMM_BLOCKS 512        // (BATCH/BM) * NCHUNK
#define FIN_BLOCKS 8
#define M0C 20.0f              // fixed softmax max bound (HW-verified exact r5/r6/r8/r9)

typedef __attribute__((ext_vector_type(8))) short short8_t;  // 8 bf16
typedef __attribute__((ext_vector_type(4))) float f32x4_t;

__device__ __forceinline__ float neg_log_expected(int c) {
    const float log_vp1 = 11.5129354649f;   // log(100001)
    float p = log1pf(1.0f / (float)(c + 1)) / log_vp1;
    float E = -expm1f((float)S_SAMPLED * log1pf(-p));
    return -logf(E);
}

__device__ __forceinline__ unsigned short f2bf(float x) {
    __hip_bfloat16 h = __float2bfloat16(x);
    union { __hip_bfloat16 h; unsigned short u; } cv; cv.h = h; return cv.u;
}

// 8 f32 -> short8 bf16 (compiler emits v_cvt_pk_bf16_f32 pairs)
__device__ __forceinline__ short8_t cvt8(f32x4_t lo, f32x4_t hi) {
    short8_t r;
    r[0] = (short)f2bf(lo[0]); r[1] = (short)f2bf(lo[1]);
    r[2] = (short)f2bf(lo[2]); r[3] = (short)f2bf(lo[3]);
    r[4] = (short)f2bf(hi[0]); r[5] = (short)f2bf(hi[1]);
    r[6] = (short)f2bf(hi[2]); r[7] = (short)f2bf(hi[3]);
    return r;
}

__device__ __forceinline__ void load_lds16(const void* g, void* l) {
    __builtin_amdgcn_global_load_lds(
        (const __attribute__((address_space(1))) void*)g,
        (__attribute__((address_space(3))) void*)l, 16, 0, 0);
}

// ------------- kernel 0: prep (gather + adj only; ~3 MB) --------------------
__global__ __launch_bounds__(256) void prep_kernel(
    const float* __restrict__ W, const float* __restrict__ b,
    const int* __restrict__ sampled,
    unsigned short* __restrict__ Wg, float* __restrict__ adj,
    int* __restrict__ counter)
{
    int bid = blockIdx.x;
    if (bid == 0 && threadIdx.x == 0) *counter = 0;
    int row = bid * 2 + (threadIdx.x >> 7);   // 0..1023
    int t   = threadIdx.x & 127;              // 128 threads * 4 elems = 512
    if (t == 0) {
        if (row < S_SAMPLED) {
            int c = sampled[row];
            adj[row] = b[c] + neg_log_expected(c);
        } else adj[row] = -1e30f;
    }
    unsigned short* dst = Wg + (size_t)row * DIM + t * 4;
    if (row < S_SAMPLED) {
        float4 f = *(const float4*)(W + (size_t)sampled[row] * DIM + t * 4);
        ushort4 o;
        o.x = f2bf(f.x); o.y = f2bf(f.y); o.z = f2bf(f.z); o.w = f2bf(f.w);
        *(ushort4*)dst = o;
    } else {
        *(ushort4*)dst = make_ushort4(0, 0, 0, 0);
    }
}

// ------------- kernel 1: MFMA GEMM (A from f32 direct) + partials + true ----
// BM=64 x BN=256, BKT=32. LDS 48KB -> 3 blocks/CU. 256 thr = 4 waves (2M x 2N).
// A staged as f32 (128 B/row, proven swizzle), cast to bf16 at fragment read.
__global__ __launch_bounds__(256, 3) void gemm_partial_kernel(
    const float* __restrict__ Ay,             // y_pred f32 [BATCH][DIM]
    const unsigned short* __restrict__ Wg,    // gathered W bf16 [SPAD][DIM]
    const int*   __restrict__ sampled,
    const float* __restrict__ adj,
    const int*   __restrict__ y_true,
    const float* __restrict__ W,              // f32, true-logit gather
    const float* __restrict__ b,
    float*       __restrict__ true_v,         // [BATCH]
    float*       __restrict__ psum)           // [BATCH][NCHUNK]
{
    __shared__ __align__(16) char smem[49152 + 512];
    char* As0 = smem;                              // 8 KB (64 x 128 B f32)
    char* As1 = smem + 8192;
    char* Bs0 = smem + 16384;                      // 16 KB (256 x 64 B bf16)
    char* Bs1 = smem + 32768;
    float* reds = (float*)(smem + 49152);          // [2][64]

    // XCD-aware remap: XCD i gets stripes 16i..16i+15, all 4 chunks
    int wg = blockIdx.x;
    int sw = (wg & 7) * 64 + (wg >> 3);     // bijective, 512 blocks
    const int m0    = (sw >> 2) * BM;
    const int chunk = sw & 3;
    const int n0    = chunk * BN;

    const int tid  = threadIdx.x;
    const int lane = tid & 63;
    const int wid  = tid >> 6;
    const int wr   = wid >> 1;
    const int wc   = wid & 1;
    const int g    = lane >> 4;
    const int lcol = lane & 15;

    const char* AF = (const char*)Ay;
    const char* WB = (const char*)Wg;

    // staging: linear LDS dest, source pre-inverse-swizzled (rule #21)
    // A: rows of 128 B (32 f32); swizzle bits 4-6 ^= row&7
    int a_src[2];
#pragma unroll
    for (int it = 0; it < 2; ++it) {
        int d = it * 4096 + tid * 16;
        int row = d >> 7;
        int kb  = (d & 127) ^ ((row & 7) << 4);
        a_src[it] = (m0 + row) * (DIM * 4) + kb;
    }
    // B: rows of 64 B (32 bf16); swizzle bits 4-5 ^= col&3
    int b_src[4];
#pragma unroll
    for (int it = 0; it < 4; ++it) {
        int d = it * 4096 + tid * 16;
        int col = d >> 6;
        int kb  = (d & 63) ^ ((col & 3) << 4);
        b_src[it] = (n0 + col) * (DIM * 2) + kb;
    }

    // fragment read offsets (swizzled)
    int a_roff[2], b_roff[8];
#pragma unroll
    for (int mi = 0; mi < 2; ++mi) {
        int r = wr * 32 + mi * 16 + lcol;
        a_roff[mi] = r * 128 + ((g * 32) ^ ((r & 7) << 4));   // +^16 for hi half
    }
#pragma unroll
    for (int nj = 0; nj < 8; ++nj) {
        int c = wc * 128 + nj * 16 + lcol;
        b_roff[nj] = c * 64 + ((g * 16) ^ ((c & 3) << 4));
    }

    f32x4_t acc[2][8] = {};

#define STAGE(AsP, BsP, kt) do {                                       \
        load_lds16(AF + a_src[0] + (kt) * 128, (AsP) + tid * 16);      \
        load_lds16(AF + a_src[1] + (kt) * 128, (AsP) + 4096 + tid * 16); \
        load_lds16(WB + b_src[0] + (kt) * 64, (BsP) + tid * 16);       \
        load_lds16(WB + b_src[1] + (kt) * 64, (BsP) + 4096 + tid * 16); \
        load_lds16(WB + b_src[2] + (kt) * 64, (BsP) + 8192 + tid * 16); \
        load_lds16(WB + b_src[3] + (kt) * 64, (BsP) + 12288 + tid * 16); \
    } while (0)

#define COMPUTE(AsP, BsP) do {                                                        \
        f32x4_t lo0 = *(const f32x4_t*)((AsP) + a_roff[0]);                           \
        f32x4_t hi0 = *(const f32x4_t*)((AsP) + (a_roff[0] ^ 16));                    \
        f32x4_t lo1 = *(const f32x4_t*)((AsP) + a_roff[1]);                           \
        f32x4_t hi1 = *(const f32x4_t*)((AsP) + (a_roff[1] ^ 16));                    \
        short8_t a0 = cvt8(lo0, hi0);                                                 \
        short8_t a1 = cvt8(lo1, hi1);                                                 \
        _Pragma("unroll")                                                             \
        for (int nj = 0; nj < 8; ++nj) {                                              \
            short8_t bv = *(const short8_t*)((BsP) + b_roff[nj]);                     \
            acc[0][nj] = __builtin_amdgcn_mfma_f32_16x16x32_bf16(a0, bv, acc[0][nj], 0, 0, 0); \
            acc[1][nj] = __builtin_amdgcn_mfma_f32_16x16x32_bf16(a1, bv, acc[1][nj], 0, 0, 0); \
        }                                                                             \
    } while (0)

    // ---- K loop: counted-vmcnt double-buffer; invariant 12 loads in flight ----
    __builtin_amdgcn_sched_barrier(0);
    STAGE(As0, Bs0, 0);
    STAGE(As1, Bs1, 1);
#pragma unroll
    for (int t = 0; t < KTILES; ++t) {
        if (t < KTILES - 1) asm volatile("s_waitcnt vmcnt(6)" ::: "memory");
        else                asm volatile("s_waitcnt vmcnt(0)" ::: "memory");
        __builtin_amdgcn_s_barrier();
        __builtin_amdgcn_sched_barrier(0);
        const char* AsP = (t & 1) ? As1 : As0;
        const char* BsP = (t & 1) ? Bs1 : Bs0;
        __builtin_amdgcn_s_setprio(1);
        COMPUTE(AsP, BsP);
        __builtin_amdgcn_s_setprio(0);
        __builtin_amdgcn_sched_barrier(0);
        __builtin_amdgcn_s_barrier();
        if (t + 2 < KTILES) STAGE((t & 1) ? As1 : As0, (t & 1) ? Bs1 : Bs0, t + 2);
    }
    __builtin_amdgcn_sched_barrier(0);

    // ---- true logits for this block's 16 rows (4 rows/wave), f32 exact ----
#pragma unroll
    for (int rr = 0; rr < 4; ++rr) {
        int row = m0 + chunk * 16 + wid * 4 + rr;
        int lab = y_true[row];
        f32x4_t p0 = *(const f32x4_t*)(Ay + (size_t)row * DIM + lane * 8);
        f32x4_t p1 = *(const f32x4_t*)(Ay + (size_t)row * DIM + lane * 8 + 4);
        f32x4_t w0 = *(const f32x4_t*)(W + (size_t)lab * DIM + lane * 8);
        f32x4_t w1 = *(const f32x4_t*)(W + (size_t)lab * DIM + lane * 8 + 4);
        float s = p0[0] * w0[0] + p0[1] * w0[1] + p0[2] * w0[2] + p0[3] * w0[3]
                + p1[0] * w1[0] + p1[1] * w1[1] + p1[2] * w1[2] + p1[3] * w1[3];
#pragma unroll
        for (int off = 32; off; off >>= 1) s += __shfl_xor(s, off);
        if (lane == 0) true_v[row] = s + b[lab] + neg_log_expected(lab);
    }

    // ---- epilogue: adj + hit mask, fixed-max partial sum of exp(x - M0) ----
    // C layout: col = lane&15, row = (lane>>4)*4 + r
    int   labs[2][4];
    float srow[2][4];
#pragma unroll
    for (int mi = 0; mi < 2; ++mi)
#pragma unroll
        for (int r = 0; r < 4; ++r) {
            labs[mi][r] = y_true[m0 + wr * 32 + mi * 16 + g * 4 + r];
            srow[mi][r] = 0.f;
        }

    float ajv[8]; int scv[8];
#pragma unroll
    for (int nj = 0; nj < 8; ++nj) {
        int cg = n0 + wc * 128 + nj * 16 + lcol;
        ajv[nj] = adj[cg];
        scv[nj] = (cg < S_SAMPLED) ? sampled[cg] : -2147483647;
    }

#pragma unroll
    for (int mi = 0; mi < 2; ++mi)
#pragma unroll
        for (int nj = 0; nj < 8; ++nj) {
#pragma unroll
            for (int r = 0; r < 4; ++r) {
                float x = acc[mi][nj][r] + ajv[nj];
                if (scv[nj] == labs[mi][r]) x -= 1e9f;
                srow[mi][r] += expf(x - M0C);   // hit/pad -> exp(-huge) = 0
            }
        }

#pragma unroll
    for (int s = 1; s < 16; s <<= 1)
#pragma unroll
        for (int mi = 0; mi < 2; ++mi)
#pragma unroll
            for (int r = 0; r < 4; ++r)
                srow[mi][r] += __shfl_xor(srow[mi][r], s);
    if (lcol == 0) {
#pragma unroll
        for (int mi = 0; mi < 2; ++mi)
#pragma unroll
            for (int r = 0; r < 4; ++r)
                reds[wc * 64 + wr * 32 + mi * 16 + g * 4 + r] = srow[mi][r];
    }
    __syncthreads();

    if (tid < BM)
        psum[(size_t)(m0 + tid) * NCHUNK + chunk] = reds[tid] + reds[64 + tid];
#undef STAGE
#undef COMPUTE
}

// ------------- kernel 2: parallel finalize (8 blocks + counter tail) --------
__global__ __launch_bounds__(1024) void finalize_kernel(
    const float* __restrict__ psum, const float* __restrict__ true_v,
    float* __restrict__ partial, int* __restrict__ counter,
    float* __restrict__ out)
{
    __shared__ float sm[1024];
    __shared__ int s_last;
    int r = blockIdx.x * 1024 + threadIdx.x;
    float4 p0 = *(const float4*)(psum + (size_t)r * NCHUNK);
    float t = true_v[r];
    float s = p0.x + p0.y + p0.z + p0.w + expf(t - M0C);
    sm[threadIdx.x] = logf(s) + M0C - t;
    __syncthreads();
    for (int st = 512; st; st >>= 1) {
        if (threadIdx.x < st) sm[threadIdx.x] += sm[threadIdx.x + st];
        __syncthreads();
    }
    if (threadIdx.x == 0) {
        partial[blockIdx.x] = sm[0];
        __threadfence();
        int old = atomicAdd(counter, 1);
        s_last = (old == FIN_BLOCKS - 1) ? 1 : 0;
    }
    __syncthreads();
    if (!s_last || threadIdx.x != 0) return;
    __threadfence();
    float tot = 0.f;
#pragma unroll
    for (int i = 0; i < FIN_BLOCKS; ++i) tot += partial[i];
    out[0] = tot / (float)BATCH;
}

extern "C" void kernel_launch(void* const* d_in, const int* in_sizes, int n_in,
                              void* d_out, int out_size, void* d_ws, size_t ws_size,
                              hipStream_t stream) {
    const int*   y_true  = (const int*)d_in[0];
    const float* y_pred  = (const float*)d_in[1];
    const float* W       = (const float*)d_in[2];
    const float* b       = (const float*)d_in[3];
    const int*   sampled = (const int*)d_in[4];

    char* ws = (char*)d_ws;
    unsigned short* Wg = (unsigned short*)ws;                     // 1 MB
    float* adj     = (float*)(ws + 1048576);                      // 4 KB
    float* true_v  = (float*)(ws + 1052672);                      // 32 KB
    float* psum    = (float*)(ws + 1085440);                      // 128 KB
    float* partial = (float*)(ws + 1216512);                      // 32 B
    int*   counter = (int*)(ws + 1216576);                        // 4 B

    prep_kernel<<<512, 256, 0, stream>>>(W, b, sampled, Wg, adj, counter);
    gemm_partial_kernel<<<GEMM_BLOCKS, 256, 0, stream>>>(
        y_pred, Wg, sampled, adj, y_true, W, b, true_v, psum);
    finalize_kernel<<<FIN_BLOCKS, 1024, 0, stream>>>(
        psum, true_v, partial, counter, (float*)d_out);
}

// Round 12
// 33.883 us; speedup vs baseline: 1.1200x; 1.1200x over previous
//
#include <hip/hip_runtime.h>
#include <hip/hip_bf16.h>
#include <math.h>

#define S_SAMPLED 1000
#define SPAD      1024
#define DIM       512
#define BATCH     8192

#define BM 128
#define BN 128
#define BKT 64                 // K per tile (128 B bf16)
#define KTILES (DIM / BKT)     // 8
#define NCHUNK 8               // SPAD / BN
#define GEMM_BLOCKS 512        // (BATCH/BM) * NCHUNK
#define FIN_BLOCKS 8
#define M0C 20.0f              // fixed softmax max bound (HW-verified exact r5/r6/r8/r9)

typedef __attribute__((ext_vector_type(8))) short short8_t;  // 8 bf16
typedef __attribute__((ext_vector_type(4))) float f32x4_t;

__device__ __forceinline__ float neg_log_expected(int c) {
    const float log_vp1 = 11.5129354649f;   // log(100001)
    float p = log1pf(1.0f / (float)(c + 1)) / log_vp1;
    float E = -expm1f((float)S_SAMPLED * log1pf(-p));
    return -logf(E);
}

__device__ __forceinline__ unsigned short f2bf(float x) {
    __hip_bfloat16 h = __float2bfloat16(x);
    union { __hip_bfloat16 h; unsigned short u; } cv; cv.h = h; return cv.u;
}

__device__ __forceinline__ float b2f(short u) {
    union { float f; unsigned u; } c;
    c.u = ((unsigned)(unsigned short)u) << 16;
    return c.f;
}

__device__ __forceinline__ void load_lds16(const void* g, void* l) {
    __builtin_amdgcn_global_load_lds(
        (const __attribute__((address_space(1))) void*)g,
        (__attribute__((address_space(3))) void*)l, 16, 0, 0);
}

// involution on byte addr: bits 4-6 ^= row&7 (rows are 128B apart)
__device__ __forceinline__ int swz(int lin) { return lin ^ (((lin >> 7) & 7) << 4); }

// ------------- kernel 0: prep ------------------------------------------------
// blocks 0..511   : gather+cast W[sampled] -> Wg bf16, compute adj (2 rows/blk)
// blocks 512..1535: pure cast y_pred f32 -> bf16 (4096 elems/blk, 16/thread)
__global__ __launch_bounds__(256) void prep_kernel(
    const float* __restrict__ y_pred, const float* __restrict__ W,
    const float* __restrict__ b, const int* __restrict__ sampled,
    unsigned short* __restrict__ Wg, float* __restrict__ adj,
    unsigned short* __restrict__ ypredB, int* __restrict__ counter)
{
    int bid = blockIdx.x;
    if (bid == 0 && threadIdx.x == 0) *counter = 0;
    if (bid < 512) {
        int row = bid * 2 + (threadIdx.x >> 7);   // 0..1023
        int t   = threadIdx.x & 127;              // 128 threads * 4 elems
        if (t == 0) {
            if (row < S_SAMPLED) {
                int c = sampled[row];
                adj[row] = b[c] + neg_log_expected(c);
            } else adj[row] = -1e30f;
        }
        unsigned short* dst = Wg + (size_t)row * DIM + t * 4;
        if (row < S_SAMPLED) {
            float4 f = *(const float4*)(W + (size_t)sampled[row] * DIM + t * 4);
            ushort4 o;
            o.x = f2bf(f.x); o.y = f2bf(f.y); o.z = f2bf(f.z); o.w = f2bf(f.w);
            *(ushort4*)dst = o;
        } else {
            *(ushort4*)dst = make_ushort4(0, 0, 0, 0);
        }
    } else {
        int i = (bid - 512) * 4096 + threadIdx.x * 16;
#pragma unroll
        for (int h = 0; h < 2; ++h) {
            float4 f0 = *(const float4*)(y_pred + i + h * 8);
            float4 f1 = *(const float4*)(y_pred + i + h * 8 + 4);
            uint4 o;
            o.x = (unsigned)f2bf(f0.x) | ((unsigned)f2bf(f0.y) << 16);
            o.y = (unsigned)f2bf(f0.z) | ((unsigned)f2bf(f0.w) << 16);
            o.z = (unsigned)f2bf(f1.x) | ((unsigned)f2bf(f1.y) << 16);
            o.w = (unsigned)f2bf(f1.z) | ((unsigned)f2bf(f1.w) << 16);
            *(uint4*)(ypredB + i + h * 8) = o;
        }
    }
}

// ------------- kernel 1: MFMA GEMM + partial sums + true logits -------------
// BM=128 x BN=128, LDS 66KB -> 2 blocks/CU. 512 threads = 8 waves (4M x 2N).
// Grid 512, XCD-swizzled so each XCD owns 8 complete m-stripes.
// Chunk block c of stripe s also computes true logits for rows m0+16c..+15.
__global__ __launch_bounds__(512, 4) void gemm_partial_kernel(
    const unsigned short* __restrict__ Abf,   // y_pred bf16 [BATCH][DIM]
    const unsigned short* __restrict__ Wg,    // gathered W bf16 [SPAD][DIM]
    const int*   __restrict__ sampled,
    const float* __restrict__ adj,
    const int*   __restrict__ y_true,
    const float* __restrict__ W,              // f32, for true-logit gather
    const float* __restrict__ b,
    float*       __restrict__ true_v,         // [BATCH]
    float*       __restrict__ psum)           // [BATCH][NCHUNK]
{
    __shared__ __align__(16) char smem[65536 + 1024];
    char* As0 = smem;                              // 16 KB
    char* As1 = smem + 16384;
    char* Bs0 = smem + 32768;                      // 16 KB
    char* Bs1 = smem + 49152;
    float* reds = (float*)(smem + 65536);          // [2][128]

    // XCD-aware remap: XCD i gets sw 64i..64i+63 = stripes 8i..8i+7, all chunks
    int wg = blockIdx.x;
    int sw = (wg & 7) * 64 + (wg >> 3);     // bijective, 512 blocks
    const int m0    = (sw >> 3) * BM;
    const int chunk = sw & 7;
    const int n0    = chunk * BN;

    const int tid  = threadIdx.x;
    const int lane = tid & 63;
    const int wid  = tid >> 6;
    const int wr   = wid >> 1;
    const int wc   = wid & 1;
    const int g    = lane >> 4;
    const int lcol = lane & 15;

    const char* AB = (const char*)Abf;
    const char* WB = (const char*)Wg;

    // staging: linear LDS dest (tid*16), source pre-inverse-swizzled (rule #21)
    int a_src[2], b_src[2];
#pragma unroll
    for (int it = 0; it < 2; ++it) {
        int d = it * 8192 + tid * 16;
        int row = d >> 7;
        int kb  = (d & 127) ^ ((row & 7) << 4);
        a_src[it] = (m0 + row) * (DIM * 2) + kb;
        b_src[it] = (n0 + row) * (DIM * 2) + kb;
    }

    int a_roff[2][2], b_roff[4][2];
#pragma unroll
    for (int mi = 0; mi < 2; ++mi)
#pragma unroll
        for (int ks = 0; ks < 2; ++ks)
            a_roff[mi][ks] = swz((wr * 32 + mi * 16 + lcol) * 128 + ks * 64 + g * 16);
#pragma unroll
    for (int nj = 0; nj < 4; ++nj)
#pragma unroll
        for (int ks = 0; ks < 2; ++ks)
            b_roff[nj][ks] = swz((wc * 64 + nj * 16 + lcol) * 128 + ks * 64 + g * 16);

    f32x4_t acc[2][4] = {};

#define STAGE(AsP, BsP, kt) do {                                     \
        int kb_ = (kt) * 128;                                        \
        load_lds16(AB + a_src[0] + kb_, (AsP) + tid * 16);           \
        load_lds16(AB + a_src[1] + kb_, (AsP) + 8192 + tid * 16);    \
        load_lds16(WB + b_src[0] + kb_, (BsP) + tid * 16);           \
        load_lds16(WB + b_src[1] + kb_, (BsP) + 8192 + tid * 16);    \
    } while (0)

#define COMPUTE(AsP, BsP) do {                                                        \
        _Pragma("unroll")                                                             \
        for (int ks = 0; ks < 2; ++ks) {                                              \
            short8_t a0 = *(const short8_t*)((AsP) + a_roff[0][ks]);                  \
            short8_t a1 = *(const short8_t*)((AsP) + a_roff[1][ks]);                  \
            _Pragma("unroll")                                                         \
            for (int nj = 0; nj < 4; ++nj) {                                          \
                short8_t bv = *(const short8_t*)((BsP) + b_roff[nj][ks]);             \
                acc[0][nj] = __builtin_amdgcn_mfma_f32_16x16x32_bf16(a0, bv, acc[0][nj], 0, 0, 0); \
                acc[1][nj] = __builtin_amdgcn_mfma_f32_16x16x32_bf16(a1, bv, acc[1][nj], 0, 0, 0); \
            }                                                                         \
        }                                                                             \
    } while (0)

    // ---- K loop: counted-vmcnt double-buffer (T3/T4), raw barriers ----
    __builtin_amdgcn_sched_barrier(0);
    STAGE(As0, Bs0, 0);
    STAGE(As1, Bs1, 1);
#pragma unroll
    for (int t = 0; t < KTILES; ++t) {
        if (t < KTILES - 1) asm volatile("s_waitcnt vmcnt(4)" ::: "memory");
        else                asm volatile("s_waitcnt vmcnt(0)" ::: "memory");
        __builtin_amdgcn_s_barrier();
        __builtin_amdgcn_sched_barrier(0);
        const char* AsP = (t & 1) ? As1 : As0;
        const char* BsP = (t & 1) ? Bs1 : Bs0;
        __builtin_amdgcn_s_setprio(1);
        COMPUTE(AsP, BsP);
        __builtin_amdgcn_s_setprio(0);
        __builtin_amdgcn_sched_barrier(0);
        __builtin_amdgcn_s_barrier();
        if (t + 2 < KTILES) STAGE((t & 1) ? As1 : As0, (t & 1) ? Bs1 : Bs0, t + 2);
    }
    __builtin_amdgcn_sched_barrier(0);

    // ---- true logits for this block's 16 rows (2 rows/wave) ----
    // bf16 y_pred (L2-hot) x f32 W[label], f32 accumulate.
#pragma unroll
    for (int rr = 0; rr < 2; ++rr) {
        int row = m0 + chunk * 16 + wid * 2 + rr;
        int lab = y_true[row];
        short8_t a8 = *(const short8_t*)(Abf + (size_t)row * DIM + lane * 8);
        float4 w0 = *(const float4*)(W + (size_t)lab * DIM + lane * 8);
        float4 w1 = *(const float4*)(W + (size_t)lab * DIM + lane * 8 + 4);
        float s = b2f(a8[0]) * w0.x + b2f(a8[1]) * w0.y
                + b2f(a8[2]) * w0.z + b2f(a8[3]) * w0.w
                + b2f(a8[4]) * w1.x + b2f(a8[5]) * w1.y
                + b2f(a8[6]) * w1.z + b2f(a8[7]) * w1.w;
#pragma unroll
        for (int off = 32; off; off >>= 1) s += __shfl_xor(s, off);
        if (lane == 0) true_v[row] = s + b[lab] + neg_log_expected(lab);
    }

    // ---- epilogue: adj + hit mask, fixed-max partial sum of exp(x - M0) ----
    // C layout: col = lane&15, row = (lane>>4)*4 + r
    int   labs[2][4];
    float srow[2][4];
#pragma unroll
    for (int mi = 0; mi < 2; ++mi)
#pragma unroll
        for (int r = 0; r < 4; ++r) {
            labs[mi][r] = y_true[m0 + wr * 32 + mi * 16 + g * 4 + r];
            srow[mi][r] = 0.f;
        }

    float ajv[4]; int scv[4];
#pragma unroll
    for (int nj = 0; nj < 4; ++nj) {
        int cg = n0 + wc * 64 + nj * 16 + lcol;
        ajv[nj] = adj[cg];
        scv[nj] = (cg < S_SAMPLED) ? sampled[cg] : -2147483647;
    }

#pragma unroll
    for (int mi = 0; mi < 2; ++mi)
#pragma unroll
        for (int nj = 0; nj < 4; ++nj) {
#pragma unroll
            for (int r = 0; r < 4; ++r) {
                float x = acc[mi][nj][r] + ajv[nj];
                if (scv[nj] == labs[mi][r]) x -= 1e9f;
                srow[mi][r] += expf(x - M0C);   // hit/pad -> exp(-huge) = 0
            }
        }

#pragma unroll
    for (int s = 1; s < 16; s <<= 1)
#pragma unroll
        for (int mi = 0; mi < 2; ++mi)
#pragma unroll
            for (int r = 0; r < 4; ++r)
                srow[mi][r] += __shfl_xor(srow[mi][r], s);
    if (lcol == 0) {
#pragma unroll
        for (int mi = 0; mi < 2; ++mi)
#pragma unroll
            for (int r = 0; r < 4; ++r)
                reds[wc * 128 + wr * 32 + mi * 16 + g * 4 + r] = srow[mi][r];
    }
    __syncthreads();

    if (tid < BM)
        psum[(size_t)(m0 + tid) * NCHUNK + chunk] = reds[tid] + reds[128 + tid];
#undef STAGE
#undef COMPUTE
}

// ------------- kernel 2: parallel finalize (8 blocks + counter tail) --------
__global__ __launch_bounds__(1024) void finalize_kernel(
    const float* __restrict__ psum, const float* __restrict__ true_v,
    float* __restrict__ partial, int* __restrict__ counter,
    float* __restrict__ out)
{
    __shared__ float sm[1024];
    __shared__ int s_last;
    int r = blockIdx.x * 1024 + threadIdx.x;
    float4 p0 = *(const float4*)(psum + (size_t)r * NCHUNK);
    float4 p1 = *(const float4*)(psum + (size_t)r * NCHUNK + 4);
    float t = true_v[r];
    float s = p0.x + p0.y + p0.z + p0.w
            + p1.x + p1.y + p1.z + p1.w + expf(t - M0C);
    sm[threadIdx.x] = logf(s) + M0C - t;
    __syncthreads();
    for (int st = 512; st; st >>= 1) {
        if (threadIdx.x < st) sm[threadIdx.x] += sm[threadIdx.x + st];
        __syncthreads();
    }
    if (threadIdx.x == 0) {
        partial[blockIdx.x] = sm[0];
        __threadfence();
        int old = atomicAdd(counter, 1);
        s_last = (old == FIN_BLOCKS - 1) ? 1 : 0;
    }
    __syncthreads();
    if (!s_last || threadIdx.x != 0) return;
    __threadfence();
    float tot = 0.f;
#pragma unroll
    for (int i = 0; i < FIN_BLOCKS; ++i) tot += partial[i];
    out[0] = tot / (float)BATCH;
}

extern "C" void kernel_launch(void* const* d_in, const int* in_sizes, int n_in,
                              void* d_out, int out_size, void* d_ws, size_t ws_size,
                              hipStream_t stream) {
    const int*   y_true  = (const int*)d_in[0];
    const float* y_pred  = (const float*)d_in[1];
    const float* W       = (const float*)d_in[2];
    const float* b       = (const float*)d_in[3];
    const int*   sampled = (const int*)d_in[4];

    char* ws = (char*)d_ws;
    unsigned short* ypredB = (unsigned short*)ws;                 // 8 MB
    unsigned short* Wg     = (unsigned short*)(ws + 8388608);     // 1 MB
    float* adj     = (float*)(ws + 9437184);                      // 4 KB
    float* true_v  = (float*)(ws + 9441280);                      // 32 KB
    float* psum    = (float*)(ws + 9474048);                      // 256 KB
    float* partial = (float*)(ws + 9736192);                      // 32 B
    int*   counter = (int*)(ws + 9736256);                        // 4 B

    prep_kernel<<<1536, 256, 0, stream>>>(y_pred, W, b, sampled,
                                          Wg, adj, ypredB, counter);
    gemm_partial_kernel<<<GEMM_BLOCKS, 512, 0, stream>>>(
        ypredB, Wg, sampled, adj, y_true, W, b, true_v, psum);
    finalize_kernel<<<FIN_BLOCKS, 1024, 0, stream>>>(
        psum, true_v, partial, counter, (float*)d_out);
}